// Round 6
// baseline (1259.330 us; speedup 1.0000x reference)
//
#include <hip/hip_runtime.h>
#include <cstdint>
#include <cstddef>

#define NN 50000
#define EE 500000
#define NPART 1024

// ---------------- workspace layout (float offsets) ----------------
static constexpr size_t NF   = (size_t)NN * 64;
static constexpr size_t OQ   = 0;
static constexpr size_t OKk  = OQ   + NF;
static constexpr size_t OV   = OKk  + NF;
static constexpr size_t OSK  = OV   + NF;
static constexpr size_t OBA  = OSK  + NF;
static constexpr size_t OBB  = OBA  + NF;
static constexpr size_t ORP  = OBB  + NF;                  // rp EE
static constexpr size_t OPART= ORP  + (size_t)EE;          // 1024*2 doubles
static constexpr size_t OSTF = OPART+ 4096;                // statsf 2 floats
static constexpr size_t OBN  = OSTF + 2;                   // bn sums 128 floats
static constexpr size_t OI   = OBN  + 128;                 // int area
static constexpr size_t ODEG = OI;
static constexpr size_t OOFF = ODEG + NN;
static constexpr size_t OCNT = OOFF + NN + 2;
static constexpr size_t OEL  = OCNT + NN;                  // elist EE int2

// out-row(64) = xv(1x64) * W(64x64, global, uniform scalar loads) + b
__device__ __forceinline__ void gemv64(const float (&xv)[64],
                                       const float* __restrict__ W,
                                       const float* __restrict__ b,
                                       float* __restrict__ dst) {
    for (int jch = 0; jch < 4; ++jch) {
        float ov[16];
#pragma unroll
        for (int jj = 0; jj < 16; ++jj) ov[jj] = b[jch * 16 + jj];
#pragma unroll
        for (int kk = 0; kk < 64; ++kk) {
            float xk = xv[kk];
            const float* wr = W + kk * 64 + jch * 16;
#pragma unroll
            for (int jj = 0; jj < 16; ++jj) ov[jj] = fmaf(xk, wr[jj], ov[jj]);
        }
        float4* pd = reinterpret_cast<float4*>(dst + jch * 16);
        pd[0] = make_float4(ov[0], ov[1], ov[2], ov[3]);
        pd[1] = make_float4(ov[4], ov[5], ov[6], ov[7]);
        pd[2] = make_float4(ov[8], ov[9], ov[10], ov[11]);
        pd[3] = make_float4(ov[12], ov[13], ov[14], ov[15]);
    }
}

// ---------------- rp ----------------
__global__ __launch_bounds__(256) void k_rp(const float* __restrict__ x,
                                            const int* __restrict__ ei,
                                            float* __restrict__ rp,
                                            double* __restrict__ partial) {
    int tid = threadIdx.x;
    size_t stride = (size_t)gridDim.x * 256;
    double c1 = 0.0, c2 = 0.0;
    for (size_t e = (size_t)blockIdx.x * 256 + tid; e < (size_t)EE; e += stride) {
        size_t r = (size_t)ei[e], c = (size_t)ei[EE + e];
        const float4* pa = reinterpret_cast<const float4*>(x + r * 64);
        const float4* pb = reinterpret_cast<const float4*>(x + c * 64);
        float s0 = 0.f, s1 = 0.f, s2 = 0.f, s3 = 0.f;
#pragma unroll
        for (int i = 0; i < 16; ++i) {
            float4 a = pa[i], b = pb[i];
            float dx = a.x - b.x, dy = a.y - b.y, dz = a.z - b.z, dw = a.w - b.w;
            s0 = fmaf(dx, dx, s0); s1 = fmaf(dy, dy, s1);
            s2 = fmaf(dz, dz, s2); s3 = fmaf(dw, dw, s3);
        }
        float rv = sqrtf((s0 + s1) + (s2 + s3));
        rp[e] = rv;
        c1 += (double)rv; c2 += (double)rv * (double)rv;
    }
    __shared__ double l1[256], l2[256];
    l1[tid] = c1; l2[tid] = c2;
    __syncthreads();
    for (int o = 128; o > 0; o >>= 1) {
        if (tid < o) { l1[tid] += l1[tid + o]; l2[tid] += l2[tid + o]; }
        __syncthreads();
    }
    if (tid == 0) { partial[blockIdx.x * 2] = l1[0]; partial[blockIdx.x * 2 + 1] = l2[0]; }
}

__global__ __launch_bounds__(256) void k_statsf(const double* __restrict__ partial,
                                                float* __restrict__ statsf) {
    __shared__ double l1[256], l2[256];
    int tid = threadIdx.x;
    double a = 0.0, b = 0.0;
    for (int i = tid; i < NPART; i += 256) { a += partial[2 * i]; b += partial[2 * i + 1]; }
    l1[tid] = a; l2[tid] = b;
    __syncthreads();
    for (int o = 128; o > 0; o >>= 1) {
        if (tid < o) { l1[tid] += l1[tid + o]; l2[tid] += l2[tid + o]; }
        __syncthreads();
    }
    if (tid == 0) {
        double s = l1[0], q = l2[0];
        double mean = s / (double)EE;
        double var = (q - (double)EE * mean * mean) / (double)(EE - 1);
        if (var < 0) var = 0;
        statsf[0] = (float)mean;
        statsf[1] = (float)(1.0 / (sqrt(var) + 1e-6));
    }
}

// ---------------- edge-encoder MLP (weights via uniform scalar loads) ----------------
__global__ __launch_bounds__(256) void k_mlp(const float* __restrict__ ea,
                                             const float* __restrict__ W1, const float* __restrict__ b1,
                                             const float* __restrict__ W2, const float* __restrict__ b2,
                                             const float* __restrict__ rp, const float* __restrict__ statsf,
                                             float* __restrict__ eout) {
    size_t e = (size_t)blockIdx.x * 256 + threadIdx.x;
    if (e >= (size_t)EE) return;

    float xv[64];
    const float4* px = reinterpret_cast<const float4*>(ea + e * 64);
#pragma unroll
    for (int i = 0; i < 16; ++i) {
        float4 t = px[i];
        xv[4 * i] = t.x; xv[4 * i + 1] = t.y; xv[4 * i + 2] = t.z; xv[4 * i + 3] = t.w;
    }
    float ov[64];
#pragma unroll
    for (int j = 0; j < 64; ++j) ov[j] = b2[j];
    for (int ch = 0; ch < 4; ++ch) {
        float hc[16];
#pragma unroll
        for (int t = 0; t < 16; ++t) hc[t] = b1[ch * 16 + t];
#pragma unroll
        for (int kk = 0; kk < 64; ++kk) {
            float xk = xv[kk];
            const float* wr = W1 + kk * 64 + ch * 16;
#pragma unroll
            for (int t = 0; t < 16; ++t) hc[t] = fmaf(xk, wr[t], hc[t]);
        }
#pragma unroll
        for (int t = 0; t < 16; ++t) hc[t] = fmaxf(hc[t], 0.f);
#pragma unroll
        for (int t = 0; t < 16; ++t) {
            float hk = hc[t];
            const float* wr = W2 + (ch * 16 + t) * 64;
#pragma unroll
            for (int j = 0; j < 64; ++j) ov[j] = fmaf(hk, wr[j], ov[j]);
        }
    }
    float rps = (rp[e] - statsf[0]) * statsf[1];
    float4* pd = reinterpret_cast<float4*>(eout + e * 64);
#pragma unroll
    for (int i = 0; i < 16; ++i)
        pd[i] = make_float4(ov[4 * i] + rps, ov[4 * i + 1] + rps, ov[4 * i + 2] + rps, ov[4 * i + 3] + rps);
}

// ---------------- CSR build ----------------
__global__ void k_zint(int* deg, int* cnt) {
    int i = blockIdx.x * 256 + threadIdx.x;
    if (i < NN) { deg[i] = 0; cnt[i] = 0; }
}

__global__ void k_deg(const int* __restrict__ ei, int* __restrict__ deg) {
    int e = blockIdx.x * 256 + threadIdx.x;
    if (e < EE) atomicAdd(&deg[ei[EE + e]], 1);
}

__global__ __launch_bounds__(1024) void k_scan(const int* __restrict__ deg, int* __restrict__ off) {
    __shared__ int part[1024];
    int t = threadIdx.x;
    const int chunk = (NN + 1023) / 1024;
    int lo = t * chunk, hi = min(lo + chunk, NN);
    int s = 0;
    for (int i = lo; i < hi; ++i) s += deg[i];
    part[t] = s;
    __syncthreads();
    for (int o = 1; o < 1024; o <<= 1) {
        int v = (t >= o) ? part[t - o] : 0;
        __syncthreads();
        part[t] += v;
        __syncthreads();
    }
    int base = (t == 0) ? 0 : part[t - 1];
    for (int i = lo; i < hi; ++i) { off[i] = base; base += deg[i]; }
    if (t == 0) off[NN] = EE;
}

__global__ void k_scatter(const int* __restrict__ ei, const int* __restrict__ off,
                          int* __restrict__ cnt, int2* __restrict__ elist) {
    int e = blockIdx.x * 256 + threadIdx.x;
    if (e >= EE) return;
    int r = ei[e], c = ei[EE + e];
    int pos = off[c] + atomicAdd(&cnt[c], 1);
    elist[pos] = make_int2(e, r);
}

// ---------------- node-side GEMVs: one wave = one matrix for 64 nodes ----------------
__global__ __launch_bounds__(256) void k_node(const float* __restrict__ xin,
                                              const float* __restrict__ Wq, const float* __restrict__ bq,
                                              const float* __restrict__ Wk, const float* __restrict__ bk,
                                              const float* __restrict__ Wv, const float* __restrict__ bv,
                                              const float* __restrict__ Wsk, const float* __restrict__ bsk,
                                              float* __restrict__ q, float* __restrict__ k,
                                              float* __restrict__ v, float* __restrict__ sk) {
    int lane = threadIdx.x & 63;
    int w = __builtin_amdgcn_readfirstlane(threadIdx.x >> 6);
    size_t node = (size_t)blockIdx.x * 64 + lane;
    if (node >= (size_t)NN) return;
    const float* W; const float* b; float* dst;
    if (w == 0)      { W = Wq;  b = bq;  dst = q;  }
    else if (w == 1) { W = Wk;  b = bk;  dst = k;  }
    else if (w == 2) { W = Wv;  b = bv;  dst = v;  }
    else             { W = Wsk; b = bsk; dst = sk; }
    float xv[64];
    const float4* px = reinterpret_cast<const float4*>(xin + node * 64);
#pragma unroll
    for (int i = 0; i < 16; ++i) {
        float4 t = px[i];
        xv[4 * i] = t.x; xv[4 * i + 1] = t.y; xv[4 * i + 2] = t.z; xv[4 * i + 3] = t.w;
    }
    gemv64(xv, W, b, dst + node * 64);
}

// ---------------- fused per-destination attention (lane-parallel dots, online softmax) ----------------
// wave = node. lane l owns column l (head hs=l>>4).
// alpha_h = (qk_h + e.t_h)/4 via ONE butterfly family; Sum(alpha*ee) via A_h accumulator + epilogue GEMV.
__global__ __launch_bounds__(256) void k_edge(const int* __restrict__ off,
                                              const int2* __restrict__ elist,
                                              const float* __restrict__ eptr,
                                              const float* __restrict__ Wep,
                                              const float* __restrict__ q,
                                              const float* __restrict__ kf,
                                              const float* __restrict__ vf,
                                              const float* __restrict__ skp,
                                              float* __restrict__ outb) {
    __shared__ float sAll[1024];
    int lane = threadIdx.x & 63;
    int wid = __builtin_amdgcn_readfirstlane(threadIdx.x >> 6);
    int hs = lane >> 4;
    size_t node = (size_t)blockIdx.x * 4 + wid;   // grid exact: NN/4 blocks

    // t[h][lane] = sum_c We[lane][h*16+c] * q[node][h*16+c]
    const float* __restrict__ qrow = q + node * 64;
    const float* __restrict__ wrow = Wep + (size_t)lane * 64;
    float t0 = 0.f, t1 = 0.f, t2 = 0.f, t3 = 0.f;
#pragma unroll
    for (int c = 0; c < 16; ++c) {
        t0 = fmaf(wrow[c],      qrow[c],      t0);
        t1 = fmaf(wrow[16 + c], qrow[16 + c], t1);
        t2 = fmaf(wrow[32 + c], qrow[32 + c], t2);
        t3 = fmaf(wrow[48 + c], qrow[48 + c], t3);
    }
    float qv = qrow[lane];
    float sel[4];
#pragma unroll
    for (int h = 0; h < 4; ++h) sel[h] = (hs == h) ? 1.f : 0.f;

    int p0 = off[node], p1 = off[node + 1];
    float m[4], A[4];
#pragma unroll
    for (int h = 0; h < 4; ++h) { m[h] = -INFINITY; A[h] = 0.f; }
    float s = 0.f, o = 0.f;
    bool b0 = (hs & 1) != 0, b1 = (hs & 2) != 0;

    int p = p0;
    for (; p + 4 <= p1; p += 4) {
        float er[4], kv[4], vv[4], w[4][4];
#pragma unroll
        for (int j = 0; j < 4; ++j) {
            int2 pr = elist[p + j];
            er[j] = eptr[(size_t)pr.x * 64 + lane];
            kv[j] = kf[(size_t)pr.y * 64 + lane];
            vv[j] = vf[(size_t)pr.y * 64 + lane];
        }
#pragma unroll
        for (int j = 0; j < 4; ++j) {
            float qk = qv * kv[j];
            w[j][0] = fmaf(sel[0], qk, er[j] * t0);
            w[j][1] = fmaf(sel[1], qk, er[j] * t1);
            w[j][2] = fmaf(sel[2], qk, er[j] * t2);
            w[j][3] = fmaf(sel[3], qk, er[j] * t3);
        }
#pragma unroll
        for (int j = 0; j < 4; ++j)
#pragma unroll
            for (int h = 0; h < 4; ++h) {
                float x = w[j][h];
                x += __shfl_xor(x, 1);  x += __shfl_xor(x, 2);
                x += __shfl_xor(x, 4);  x += __shfl_xor(x, 8);
                x += __shfl_xor(x, 16); x += __shfl_xor(x, 32);
                w[j][h] = x * 0.25f;    // alpha_{j,h}, identical on all lanes
            }
        float mn[4], sc[4], pe[4][4];
#pragma unroll
        for (int h = 0; h < 4; ++h) {
            mn[h] = fmaxf(fmaxf(m[h], fmaxf(w[0][h], w[1][h])), fmaxf(w[2][h], w[3][h]));
            sc[h] = __expf(m[h] - mn[h]);
            m[h] = mn[h];
        }
#pragma unroll
        for (int j = 0; j < 4; ++j)
#pragma unroll
            for (int h = 0; h < 4; ++h) pe[j][h] = __expf(w[j][h] - mn[h]);
#pragma unroll
        for (int h = 0; h < 4; ++h)
            A[h] = A[h] * sc[h] + (fmaf(pe[0][h], er[0], pe[1][h] * er[1]) +
                                   fmaf(pe[2][h], er[2], pe[3][h] * er[3]));
        float scA = b0 ? sc[1] : sc[0], scB = b0 ? sc[3] : sc[2];
        float sco = b1 ? scB : scA;
        float pown[4];
#pragma unroll
        for (int j = 0; j < 4; ++j) {
            float pA = b0 ? pe[j][1] : pe[j][0];
            float pB = b0 ? pe[j][3] : pe[j][2];
            pown[j] = b1 ? pB : pA;
        }
        s = s * sco + ((pown[0] + pown[1]) + (pown[2] + pown[3]));
        o = o * sco + (fmaf(pown[0], vv[0], pown[1] * vv[1]) +
                       fmaf(pown[2], vv[2], pown[3] * vv[3]));
    }
    for (; p < p1; ++p) {
        int2 pr = elist[p];
        float er = eptr[(size_t)pr.x * 64 + lane];
        float kv = kf[(size_t)pr.y * 64 + lane];
        float vv = vf[(size_t)pr.y * 64 + lane];
        float qk = qv * kv;
        float w[4];
        w[0] = fmaf(sel[0], qk, er * t0);
        w[1] = fmaf(sel[1], qk, er * t1);
        w[2] = fmaf(sel[2], qk, er * t2);
        w[3] = fmaf(sel[3], qk, er * t3);
#pragma unroll
        for (int h = 0; h < 4; ++h) {
            float x = w[h];
            x += __shfl_xor(x, 1);  x += __shfl_xor(x, 2);
            x += __shfl_xor(x, 4);  x += __shfl_xor(x, 8);
            x += __shfl_xor(x, 16); x += __shfl_xor(x, 32);
            w[h] = x * 0.25f;
        }
        float mn[4], sc[4], pe[4];
#pragma unroll
        for (int h = 0; h < 4; ++h) {
            mn[h] = fmaxf(m[h], w[h]);
            sc[h] = __expf(m[h] - mn[h]);
            pe[h] = __expf(w[h] - mn[h]);
            m[h] = mn[h];
            A[h] = A[h] * sc[h] + pe[h] * er;
        }
        float scA = b0 ? sc[1] : sc[0], scB = b0 ? sc[3] : sc[2];
        float sco = b1 ? scB : scA;
        float pA = b0 ? pe[1] : pe[0], pB = b0 ? pe[3] : pe[2];
        float po = b1 ? pB : pA;
        s = s * sco + po;
        o = o * sco + po * vv;
    }

    // epilogue: ee-message = (A_{hs} @ We[:, lane]); both o and ex are divided by s
    float* myA = sAll + wid * 256;
#pragma unroll
    for (int h = 0; h < 4; ++h) myA[h * 64 + lane] = A[h];
    __syncthreads();
    const float* Ah = sAll + wid * 256 + hs * 64;
    float ex = 0.f;
#pragma unroll
    for (int kk = 0; kk < 64; ++kk) ex = fmaf(Ah[kk], Wep[(size_t)kk * 64 + lane], ex);
    outb[node * 64 + lane] = (o + ex) / (s + 1e-16f) + skp[node * 64 + lane];
}

// ---------------- BN stats + BN/ReLU/residual/LN ----------------
__global__ void k_zbn(float* bn) {
    if (threadIdx.x < 128) bn[threadIdx.x] = 0.f;
}

__global__ __launch_bounds__(256) void k_bnstat(const float* __restrict__ conv, float* __restrict__ bn) {
    int tid = threadIdx.x;
    size_t idx0 = (size_t)blockIdx.x * 256 + tid;
    size_t stride = (size_t)gridDim.x * 256;
    float s = 0.f, ss = 0.f;
    for (size_t i = idx0; i < NF; i += stride) {
        float val = conv[i];
        s += val; ss += val * val;
    }
    __shared__ float l1[256], l2[256];
    l1[tid] = s; l2[tid] = ss;
    __syncthreads();
    if (tid < 64) {
        float a = l1[tid] + l1[tid + 64] + l1[tid + 128] + l1[tid + 192];
        float b = l2[tid] + l2[tid + 64] + l2[tid + 128] + l2[tid + 192];
        atomicAdd(bn + tid, a);
        atomicAdd(bn + 64 + tid, b);
    }
}

__global__ __launch_bounds__(256) void k_bnln(const float* __restrict__ conv,
                                              const float* __restrict__ xres,
                                              const float* __restrict__ bn,
                                              const float* __restrict__ g, const float* __restrict__ b,
                                              const float* __restrict__ lg, const float* __restrict__ lb,
                                              float* __restrict__ xout) {
    int tid = threadIdx.x;
    int lane = tid & 63;
    size_t row = (size_t)blockIdx.x * 4 + (tid >> 6);
    if (row >= (size_t)NN) return;
    float val = conv[row * 64 + lane];
    float mu = bn[lane] * (1.f / NN);
    float var = bn[64 + lane] * (1.f / NN) - mu * mu;
    float hn = (val - mu) * rsqrtf(var + 1e-5f) * g[lane] + b[lane];
    hn = fmaxf(hn, 0.f);
    float t = hn + xres[row * 64 + lane];
    float s = t, ss = t * t;
#pragma unroll
    for (int o = 32; o >= 1; o >>= 1) { s += __shfl_xor(s, o); ss += __shfl_xor(ss, o); }
    float mu2 = s * (1.f / 64.f);
    float var2 = ss * (1.f / 64.f) - mu2 * mu2;
    xout[row * 64 + lane] = (t - mu2) * rsqrtf(var2 + 1e-5f) * lg[lane] + lb[lane];
}

// ---------------- launch ----------------
extern "C" void kernel_launch(void* const* d_in, const int* in_sizes, int n_in,
                              void* d_out, int out_size, void* d_ws, size_t ws_size,
                              hipStream_t stream) {
    (void)in_sizes; (void)n_in; (void)out_size; (void)ws_size;
    const float* x   = (const float*)d_in[0];
    const int*   ei  = (const int*)d_in[1];
    const float* ea  = (const float*)d_in[2];
    const float* Wq  = (const float*)d_in[3];  const float* bq = (const float*)d_in[4];
    const float* Wk  = (const float*)d_in[5];  const float* bk = (const float*)d_in[6];
    const float* Wv  = (const float*)d_in[7];  const float* bv = (const float*)d_in[8];
    const float* We  = (const float*)d_in[9];
    const float* Wsk = (const float*)d_in[10]; const float* bsk = (const float*)d_in[11];
    const float* eW1 = (const float*)d_in[12]; const float* eb1 = (const float*)d_in[13];
    const float* eW2 = (const float*)d_in[14]; const float* eb2 = (const float*)d_in[15];
    const float* bng = (const float*)d_in[16]; const float* bnb = (const float*)d_in[17];
    const float* lng = (const float*)d_in[18]; const float* lnb = (const float*)d_in[19];

    float* ws = (float*)d_ws;
    float* out_x = (float*)d_out;
    float* out_e = out_x + NF;

    float* q    = ws + OQ;
    float* k    = ws + OKk;
    float* v    = ws + OV;
    float* sk   = ws + OSK;
    float* bufA = ws + OBA;
    float* bufB = ws + OBB;
    float* rp   = ws + ORP;
    double* partial = (double*)(ws + OPART);
    float* statsf   = ws + OSTF;
    float* bn   = ws + OBN;
    int* deg  = (int*)(ws + ODEG);
    int* off  = (int*)(ws + OOFF);
    int* cnt  = (int*)(ws + OCNT);
    int2* elist = (int2*)(ws + OEL);

    k_rp<<<NPART, 256, 0, stream>>>(x, ei, rp, partial);
    k_statsf<<<1, 256, 0, stream>>>(partial, statsf);
    k_mlp<<<(EE + 255) / 256, 256, 0, stream>>>(ea, eW1, eb1, eW2, eb2, rp, statsf, out_e);

    k_zint<<<(NN + 255) / 256, 256, 0, stream>>>(deg, cnt);
    k_deg<<<(EE + 255) / 256, 256, 0, stream>>>(ei, deg);
    k_scan<<<1, 1024, 0, stream>>>(deg, off);
    k_scatter<<<(EE + 255) / 256, 256, 0, stream>>>(ei, off, cnt, elist);

    const float* xin = x;
    for (int l = 0; l < 3; ++l) {
        k_node<<<(NN + 63) / 64, 256, 0, stream>>>(xin,
            Wq + (size_t)l * 4096, bq + (size_t)l * 64,
            Wk + (size_t)l * 4096, bk + (size_t)l * 64,
            Wv + (size_t)l * 4096, bv + (size_t)l * 64,
            Wsk + (size_t)l * 4096, bsk + (size_t)l * 64,
            q, k, v, sk);
        float* conv = (l == 2) ? out_x : sk;   // in-place skip add (same-element RMW only)
        k_edge<<<NN / 4, 256, 0, stream>>>(off, elist, out_e,
            We + (size_t)l * 4096, q, k, v, sk, conv);
        if (l < 2) {
            k_zbn<<<1, 128, 0, stream>>>(bn);
            k_bnstat<<<1024, 256, 0, stream>>>(conv, bn);
            float* xout = (l == 0) ? bufA : bufB;
            k_bnln<<<(NN + 3) / 4, 256, 0, stream>>>(conv, xin, bn,
                bng + (size_t)l * 64, bnb + (size_t)l * 64,
                lng + (size_t)l * 64, lnb + (size_t)l * 64, xout);
            xin = xout;
        }
    }
}

// Round 7
// 937.436 us; speedup vs baseline: 1.3434x; 1.3434x over previous
//
#include <hip/hip_runtime.h>
#include <cstdint>
#include <cstddef>

#define NN 50000
#define EE 500000
#define NPART 1024
#define NTILE 31250   // EE/16

typedef unsigned short ushort_t;
typedef __attribute__((ext_vector_type(8))) short short8;
typedef __attribute__((ext_vector_type(4))) float f32x4;

__device__ __forceinline__ ushort_t f2bf(float f) {
    unsigned u = __float_as_uint(f);
    unsigned r = (u + 0x7fffu + ((u >> 16) & 1u)) >> 16;
    return (ushort_t)r;
}
__device__ __forceinline__ float bf2f(ushort_t b) {
    return __uint_as_float(((unsigned)b) << 16);
}

// ---------------- workspace layout (float offsets) ----------------
static constexpr size_t NF   = (size_t)NN * 64;
static constexpr size_t OQ   = 0;
static constexpr size_t OKk  = OQ   + NF;
static constexpr size_t OV   = OKk  + NF;
static constexpr size_t OSK  = OV   + NF;
static constexpr size_t OBA  = OSK  + NF;
static constexpr size_t OBB  = OBA  + NF;
static constexpr size_t ORP  = OBB  + NF;                  // rp EE
static constexpr size_t OPART= ORP  + (size_t)EE;          // 1024*2 doubles
static constexpr size_t OSTF = OPART+ 4096;                // statsf 2 floats
static constexpr size_t OBN  = OSTF + 2;                   // bn sums 128 floats
static constexpr size_t OI   = OBN  + 128;                 // int area
static constexpr size_t ODEG = OI;
static constexpr size_t OOFF = ODEG + NN;
static constexpr size_t OCNT = OOFF + NN + 2;
static constexpr size_t OEL  = OCNT + NN;                  // elist EE int2 (2*EE ints)
static constexpr size_t OEEB = OEL  + (size_t)EE * 2;      // ee bf16: EE*64 ushorts = EE*32 floats

// out-row(64) = xv(1x64) * W(64x64, global, uniform scalar loads) + b
__device__ __forceinline__ void gemv64(const float (&xv)[64],
                                       const float* __restrict__ W,
                                       const float* __restrict__ b,
                                       float* __restrict__ dst) {
    for (int jch = 0; jch < 4; ++jch) {
        float ov[16];
#pragma unroll
        for (int jj = 0; jj < 16; ++jj) ov[jj] = b[jch * 16 + jj];
#pragma unroll
        for (int kk = 0; kk < 64; ++kk) {
            float xk = xv[kk];
            const float* wr = W + kk * 64 + jch * 16;
#pragma unroll
            for (int jj = 0; jj < 16; ++jj) ov[jj] = fmaf(xk, wr[jj], ov[jj]);
        }
        float4* pd = reinterpret_cast<float4*>(dst + jch * 16);
        pd[0] = make_float4(ov[0], ov[1], ov[2], ov[3]);
        pd[1] = make_float4(ov[4], ov[5], ov[6], ov[7]);
        pd[2] = make_float4(ov[8], ov[9], ov[10], ov[11]);
        pd[3] = make_float4(ov[12], ov[13], ov[14], ov[15]);
    }
}

// ---------------- rp ----------------
__global__ __launch_bounds__(256) void k_rp(const float* __restrict__ x,
                                            const int* __restrict__ ei,
                                            float* __restrict__ rp,
                                            double* __restrict__ partial) {
    int tid = threadIdx.x;
    size_t stride = (size_t)gridDim.x * 256;
    double c1 = 0.0, c2 = 0.0;
    for (size_t e = (size_t)blockIdx.x * 256 + tid; e < (size_t)EE; e += stride) {
        size_t r = (size_t)ei[e], c = (size_t)ei[EE + e];
        const float4* pa = reinterpret_cast<const float4*>(x + r * 64);
        const float4* pb = reinterpret_cast<const float4*>(x + c * 64);
        float s0 = 0.f, s1 = 0.f, s2 = 0.f, s3 = 0.f;
#pragma unroll
        for (int i = 0; i < 16; ++i) {
            float4 a = pa[i], b = pb[i];
            float dx = a.x - b.x, dy = a.y - b.y, dz = a.z - b.z, dw = a.w - b.w;
            s0 = fmaf(dx, dx, s0); s1 = fmaf(dy, dy, s1);
            s2 = fmaf(dz, dz, s2); s3 = fmaf(dw, dw, s3);
        }
        float rv = sqrtf((s0 + s1) + (s2 + s3));
        rp[e] = rv;
        c1 += (double)rv; c2 += (double)rv * (double)rv;
    }
    __shared__ double l1[256], l2[256];
    l1[tid] = c1; l2[tid] = c2;
    __syncthreads();
    for (int o = 128; o > 0; o >>= 1) {
        if (tid < o) { l1[tid] += l1[tid + o]; l2[tid] += l2[tid + o]; }
        __syncthreads();
    }
    if (tid == 0) { partial[blockIdx.x * 2] = l1[0]; partial[blockIdx.x * 2 + 1] = l2[0]; }
}

__global__ __launch_bounds__(256) void k_statsf(const double* __restrict__ partial,
                                                float* __restrict__ statsf) {
    __shared__ double l1[256], l2[256];
    int tid = threadIdx.x;
    double a = 0.0, b = 0.0;
    for (int i = tid; i < NPART; i += 256) { a += partial[2 * i]; b += partial[2 * i + 1]; }
    l1[tid] = a; l2[tid] = b;
    __syncthreads();
    for (int o = 128; o > 0; o >>= 1) {
        if (tid < o) { l1[tid] += l1[tid + o]; l2[tid] += l2[tid + o]; }
        __syncthreads();
    }
    if (tid == 0) {
        double s = l1[0], q = l2[0];
        double mean = s / (double)EE;
        double var = (q - (double)EE * mean * mean) / (double)(EE - 1);
        if (var < 0) var = 0;
        statsf[0] = (float)mean;
        statsf[1] = (float)(1.0 / (sqrt(var) + 1e-6));
    }
}

// ---------------- edge-encoder MLP (weights via uniform scalar loads) ----------------
__global__ __launch_bounds__(256) void k_mlp(const float* __restrict__ ea,
                                             const float* __restrict__ W1, const float* __restrict__ b1,
                                             const float* __restrict__ W2, const float* __restrict__ b2,
                                             const float* __restrict__ rp, const float* __restrict__ statsf,
                                             float* __restrict__ eout) {
    size_t e = (size_t)blockIdx.x * 256 + threadIdx.x;
    if (e >= (size_t)EE) return;

    float xv[64];
    const float4* px = reinterpret_cast<const float4*>(ea + e * 64);
#pragma unroll
    for (int i = 0; i < 16; ++i) {
        float4 t = px[i];
        xv[4 * i] = t.x; xv[4 * i + 1] = t.y; xv[4 * i + 2] = t.z; xv[4 * i + 3] = t.w;
    }
    float ov[64];
#pragma unroll
    for (int j = 0; j < 64; ++j) ov[j] = b2[j];
    for (int ch = 0; ch < 4; ++ch) {
        float hc[16];
#pragma unroll
        for (int t = 0; t < 16; ++t) hc[t] = b1[ch * 16 + t];
#pragma unroll
        for (int kk = 0; kk < 64; ++kk) {
            float xk = xv[kk];
            const float* wr = W1 + kk * 64 + ch * 16;
#pragma unroll
            for (int t = 0; t < 16; ++t) hc[t] = fmaf(xk, wr[t], hc[t]);
        }
#pragma unroll
        for (int t = 0; t < 16; ++t) hc[t] = fmaxf(hc[t], 0.f);
#pragma unroll
        for (int t = 0; t < 16; ++t) {
            float hk = hc[t];
            const float* wr = W2 + (ch * 16 + t) * 64;
#pragma unroll
            for (int j = 0; j < 64; ++j) ov[j] = fmaf(hk, wr[j], ov[j]);
        }
    }
    float rps = (rp[e] - statsf[0]) * statsf[1];
    float4* pd = reinterpret_cast<float4*>(eout + e * 64);
#pragma unroll
    for (int i = 0; i < 16; ++i)
        pd[i] = make_float4(ov[4 * i] + rps, ov[4 * i + 1] + rps, ov[4 * i + 2] + rps, ov[4 * i + 3] + rps);
}

// ---------------- CSR build ----------------
__global__ void k_zint(int* deg, int* cnt) {
    int i = blockIdx.x * 256 + threadIdx.x;
    if (i < NN) { deg[i] = 0; cnt[i] = 0; }
}

__global__ void k_deg(const int* __restrict__ ei, int* __restrict__ deg) {
    int e = blockIdx.x * 256 + threadIdx.x;
    if (e < EE) atomicAdd(&deg[ei[EE + e]], 1);
}

__global__ __launch_bounds__(1024) void k_scan(const int* __restrict__ deg, int* __restrict__ off) {
    __shared__ int part[1024];
    int t = threadIdx.x;
    const int chunk = (NN + 1023) / 1024;
    int lo = t * chunk, hi = min(lo + chunk, NN);
    int s = 0;
    for (int i = lo; i < hi; ++i) s += deg[i];
    part[t] = s;
    __syncthreads();
    for (int o = 1; o < 1024; o <<= 1) {
        int v = (t >= o) ? part[t - o] : 0;
        __syncthreads();
        part[t] += v;
        __syncthreads();
    }
    int base = (t == 0) ? 0 : part[t - 1];
    for (int i = lo; i < hi; ++i) { off[i] = base; base += deg[i]; }
    if (t == 0) off[NN] = EE;
}

__global__ void k_scatter(const int* __restrict__ ei, const int* __restrict__ off,
                          int* __restrict__ cnt, int2* __restrict__ elist) {
    int e = blockIdx.x * 256 + threadIdx.x;
    if (e >= EE) return;
    int r = ei[e], c = ei[EE + e];
    int pos = off[c] + atomicAdd(&cnt[c], 1);
    elist[pos] = make_int2(e, r);
}

// ---------------- node-side GEMVs: one wave = one matrix for 64 nodes ----------------
__global__ __launch_bounds__(256) void k_node(const float* __restrict__ xin,
                                              const float* __restrict__ Wq, const float* __restrict__ bq,
                                              const float* __restrict__ Wk, const float* __restrict__ bk,
                                              const float* __restrict__ Wv, const float* __restrict__ bv,
                                              const float* __restrict__ Wsk, const float* __restrict__ bsk,
                                              float* __restrict__ q, float* __restrict__ k,
                                              float* __restrict__ v, float* __restrict__ sk) {
    int lane = threadIdx.x & 63;
    int w = __builtin_amdgcn_readfirstlane(threadIdx.x >> 6);
    size_t node = (size_t)blockIdx.x * 64 + lane;
    if (node >= (size_t)NN) return;
    const float* W; const float* b; float* dst;
    if (w == 0)      { W = Wq;  b = bq;  dst = q;  }
    else if (w == 1) { W = Wk;  b = bk;  dst = k;  }
    else if (w == 2) { W = Wv;  b = bv;  dst = v;  }
    else             { W = Wsk; b = bsk; dst = sk; }
    float xv[64];
    const float4* px = reinterpret_cast<const float4*>(xin + node * 64);
#pragma unroll
    for (int i = 0; i < 16; ++i) {
        float4 t = px[i];
        xv[4 * i] = t.x; xv[4 * i + 1] = t.y; xv[4 * i + 2] = t.z; xv[4 * i + 3] = t.w;
    }
    gemv64(xv, W, b, dst + node * 64);
}

// ---------------- ee = e @ We  (E x 64 @ 64 x 64) via MFMA, bf16 out ----------------
// mfma_f32_16x16x32_bf16: A-frag lane l: A[row=l&15][k=(l>>4)*8+j]; B-frag: B[k=(l>>4)*8+j][n=l&15]
// C/D: col=lane&15, row=(lane>>4)*4+reg   [verified m89]
__global__ __launch_bounds__(256) void k_ee(const float* __restrict__ e32,
                                            const float* __restrict__ We,
                                            ushort_t* __restrict__ eebf) {
    int lane = threadIdx.x & 63;
    int col = lane & 15, kg = lane >> 4;
    int gw = blockIdx.x * 4 + (threadIdx.x >> 6);
    int nw = gridDim.x * 4;

    short8 bfr[4][2];
#pragma unroll
    for (int n = 0; n < 4; ++n)
#pragma unroll
        for (int ks = 0; ks < 2; ++ks)
#pragma unroll
            for (int j = 0; j < 8; ++j)
                bfr[n][ks][j] = (short)f2bf(We[(size_t)(ks * 32 + kg * 8 + j) * 64 + n * 16 + col]);

    for (int t = gw; t < NTILE; t += nw) {
        const float* ar = e32 + (size_t)(t * 16 + col) * 64 + kg * 8;
        f32x4 f0 = *reinterpret_cast<const f32x4*>(ar);
        f32x4 f1 = *reinterpret_cast<const f32x4*>(ar + 4);
        f32x4 f2 = *reinterpret_cast<const f32x4*>(ar + 32);
        f32x4 f3 = *reinterpret_cast<const f32x4*>(ar + 36);
        short8 a0, a1;
#pragma unroll
        for (int j = 0; j < 4; ++j) {
            a0[j] = (short)f2bf(f0[j]); a0[4 + j] = (short)f2bf(f1[j]);
            a1[j] = (short)f2bf(f2[j]); a1[4 + j] = (short)f2bf(f3[j]);
        }
#pragma unroll
        for (int n = 0; n < 4; ++n) {
            f32x4 acc = {0.f, 0.f, 0.f, 0.f};
            acc = __builtin_amdgcn_mfma_f32_16x16x32_bf16(a0, bfr[n][0], acc, 0, 0, 0);
            acc = __builtin_amdgcn_mfma_f32_16x16x32_bf16(a1, bfr[n][1], acc, 0, 0, 0);
            ushort_t* drow = eebf + (size_t)(t * 16 + kg * 4) * 64 + n * 16 + col;
#pragma unroll
            for (int r = 0; r < 4; ++r) drow[(size_t)r * 64] = f2bf(acc[r]);
        }
    }
}

// ---------------- fused per-destination attention (head-local reduces, online softmax) ----------------
// wave = node; lane l owns column l; each 16-lane group = one head (independent m,s,o).
__global__ __launch_bounds__(256) void k_edge(const int* __restrict__ off,
                                              const int2* __restrict__ elist,
                                              const ushort_t* __restrict__ eebf,
                                              const float* __restrict__ q,
                                              const float* __restrict__ kf,
                                              const float* __restrict__ vf,
                                              const float* __restrict__ skp,
                                              float* __restrict__ outb) {
    int lane = threadIdx.x & 63;
    int wid = threadIdx.x >> 6;
    size_t node = (size_t)blockIdx.x * 4 + wid;   // grid exact: NN/4

    float qv = q[node * 64 + lane];
    int p0 = off[node], p1 = off[node + 1];
    float m = -INFINITY, s = 0.f, o = 0.f;

    int p = p0;
    for (; p + 2 <= p1; p += 2) {
        int2 pr0 = elist[p], pr1 = elist[p + 1];
        float er0 = bf2f(eebf[(size_t)pr0.x * 64 + lane]);
        float kv0 = kf[(size_t)pr0.y * 64 + lane];
        float vv0 = vf[(size_t)pr0.y * 64 + lane];
        float er1 = bf2f(eebf[(size_t)pr1.x * 64 + lane]);
        float kv1 = kf[(size_t)pr1.y * 64 + lane];
        float vv1 = vf[(size_t)pr1.y * 64 + lane];
        float d0 = qv * (kv0 + er0);
        float d1 = qv * (kv1 + er1);
        d0 += __shfl_xor(d0, 1); d1 += __shfl_xor(d1, 1);
        d0 += __shfl_xor(d0, 2); d1 += __shfl_xor(d1, 2);
        d0 += __shfl_xor(d0, 4); d1 += __shfl_xor(d1, 4);
        d0 += __shfl_xor(d0, 8); d1 += __shfl_xor(d1, 8);
        float a0 = d0 * 0.25f, a1 = d1 * 0.25f;
        float mn = fmaxf(m, fmaxf(a0, a1));
        float sc = __expf(m - mn);
        float p0e = __expf(a0 - mn), p1e = __expf(a1 - mn);
        s = s * sc + (p0e + p1e);
        o = o * sc + fmaf(p0e, vv0 + er0, p1e * (vv1 + er1));
        m = mn;
    }
    if (p < p1) {
        int2 pr = elist[p];
        float er = bf2f(eebf[(size_t)pr.x * 64 + lane]);
        float kv = kf[(size_t)pr.y * 64 + lane];
        float vv = vf[(size_t)pr.y * 64 + lane];
        float d = qv * (kv + er);
        d += __shfl_xor(d, 1); d += __shfl_xor(d, 2);
        d += __shfl_xor(d, 4); d += __shfl_xor(d, 8);
        float a = d * 0.25f;
        float mn = fmaxf(m, a);
        float sc = __expf(m - mn);
        float pe = __expf(a - mn);
        s = s * sc + pe;
        o = o * sc + pe * (vv + er);
        m = mn;
    }
    outb[node * 64 + lane] = o / (s + 1e-16f) + skp[node * 64 + lane];
}

// ---------------- BN stats + BN/ReLU/residual/LN ----------------
__global__ void k_zbn(float* bn) {
    if (threadIdx.x < 128) bn[threadIdx.x] = 0.f;
}

__global__ __launch_bounds__(256) void k_bnstat(const float* __restrict__ conv, float* __restrict__ bn) {
    int tid = threadIdx.x;
    size_t idx0 = (size_t)blockIdx.x * 256 + tid;
    size_t stride = (size_t)gridDim.x * 256;
    float s = 0.f, ss = 0.f;
    for (size_t i = idx0; i < NF; i += stride) {
        float val = conv[i];
        s += val; ss += val * val;
    }
    __shared__ float l1[256], l2[256];
    l1[tid] = s; l2[tid] = ss;
    __syncthreads();
    if (tid < 64) {
        float a = l1[tid] + l1[tid + 64] + l1[tid + 128] + l1[tid + 192];
        float b = l2[tid] + l2[tid + 64] + l2[tid + 128] + l2[tid + 192];
        atomicAdd(bn + tid, a);
        atomicAdd(bn + 64 + tid, b);
    }
}

__global__ __launch_bounds__(256) void k_bnln(const float* __restrict__ conv,
                                              const float* __restrict__ xres,
                                              const float* __restrict__ bn,
                                              const float* __restrict__ g, const float* __restrict__ b,
                                              const float* __restrict__ lg, const float* __restrict__ lb,
                                              float* __restrict__ xout) {
    int tid = threadIdx.x;
    int lane = tid & 63;
    size_t row = (size_t)blockIdx.x * 4 + (tid >> 6);
    if (row >= (size_t)NN) return;
    float val = conv[row * 64 + lane];
    float mu = bn[lane] * (1.f / NN);
    float var = bn[64 + lane] * (1.f / NN) - mu * mu;
    float hn = (val - mu) * rsqrtf(var + 1e-5f) * g[lane] + b[lane];
    hn = fmaxf(hn, 0.f);
    float t = hn + xres[row * 64 + lane];
    float s = t, ss = t * t;
#pragma unroll
    for (int o = 32; o >= 1; o >>= 1) { s += __shfl_xor(s, o); ss += __shfl_xor(ss, o); }
    float mu2 = s * (1.f / 64.f);
    float var2 = ss * (1.f / 64.f) - mu2 * mu2;
    xout[row * 64 + lane] = (t - mu2) * rsqrtf(var2 + 1e-5f) * lg[lane] + lb[lane];
}

// ---------------- launch ----------------
extern "C" void kernel_launch(void* const* d_in, const int* in_sizes, int n_in,
                              void* d_out, int out_size, void* d_ws, size_t ws_size,
                              hipStream_t stream) {
    (void)in_sizes; (void)n_in; (void)out_size; (void)ws_size;
    const float* x   = (const float*)d_in[0];
    const int*   ei  = (const int*)d_in[1];
    const float* ea  = (const float*)d_in[2];
    const float* Wq  = (const float*)d_in[3];  const float* bq = (const float*)d_in[4];
    const float* Wk  = (const float*)d_in[5];  const float* bk = (const float*)d_in[6];
    const float* Wv  = (const float*)d_in[7];  const float* bv = (const float*)d_in[8];
    const float* We  = (const float*)d_in[9];
    const float* Wsk = (const float*)d_in[10]; const float* bsk = (const float*)d_in[11];
    const float* eW1 = (const float*)d_in[12]; const float* eb1 = (const float*)d_in[13];
    const float* eW2 = (const float*)d_in[14]; const float* eb2 = (const float*)d_in[15];
    const float* bng = (const float*)d_in[16]; const float* bnb = (const float*)d_in[17];
    const float* lng = (const float*)d_in[18]; const float* lnb = (const float*)d_in[19];

    float* ws = (float*)d_ws;
    float* out_x = (float*)d_out;
    float* out_e = out_x + NF;

    float* q    = ws + OQ;
    float* k    = ws + OKk;
    float* v    = ws + OV;
    float* sk   = ws + OSK;
    float* bufA = ws + OBA;
    float* bufB = ws + OBB;
    float* rp   = ws + ORP;
    double* partial = (double*)(ws + OPART);
    float* statsf   = ws + OSTF;
    float* bn   = ws + OBN;
    int* deg  = (int*)(ws + ODEG);
    int* off  = (int*)(ws + OOFF);
    int* cnt  = (int*)(ws + OCNT);
    int2* elist = (int2*)(ws + OEL);
    ushort_t* eebf = (ushort_t*)(ws + OEEB);

    k_rp<<<NPART, 256, 0, stream>>>(x, ei, rp, partial);
    k_statsf<<<1, 256, 0, stream>>>(partial, statsf);
    k_mlp<<<(EE + 255) / 256, 256, 0, stream>>>(ea, eW1, eb1, eW2, eb2, rp, statsf, out_e);

    k_zint<<<(NN + 255) / 256, 256, 0, stream>>>(deg, cnt);
    k_deg<<<(EE + 255) / 256, 256, 0, stream>>>(ei, deg);
    k_scan<<<1, 1024, 0, stream>>>(deg, off);
    k_scatter<<<(EE + 255) / 256, 256, 0, stream>>>(ei, off, cnt, elist);

    const float* xin = x;
    for (int l = 0; l < 3; ++l) {
        k_node<<<(NN + 63) / 64, 256, 0, stream>>>(xin,
            Wq + (size_t)l * 4096, bq + (size_t)l * 64,
            Wk + (size_t)l * 4096, bk + (size_t)l * 64,
            Wv + (size_t)l * 4096, bv + (size_t)l * 64,
            Wsk + (size_t)l * 4096, bsk + (size_t)l * 64,
            q, k, v, sk);
        k_ee<<<512, 256, 0, stream>>>(out_e, We + (size_t)l * 4096, eebf);
        float* conv = (l == 2) ? out_x : sk;   // in-place skip add (same-element RMW only)
        k_edge<<<NN / 4, 256, 0, stream>>>(off, elist, eebf, q, k, v, sk, conv);
        if (l < 2) {
            k_zbn<<<1, 128, 0, stream>>>(bn);
            k_bnstat<<<1024, 256, 0, stream>>>(conv, bn);
            float* xout = (l == 0) ? bufA : bufB;
            k_bnln<<<(NN + 3) / 4, 256, 0, stream>>>(conv, xin, bn,
                bng + (size_t)l * 64, bnb + (size_t)l * 64,
                lng + (size_t)l * 64, lnb + (size_t)l * 64, xout);
            xin = xout;
        }
    }
}